// Round 3
// baseline (820.743 us; speedup 1.0000x reference)
//
#include <hip/hip_runtime.h>
#include <stdint.h>

typedef unsigned uint;
typedef unsigned long long ull;

#define DIMS   4096
#define NT     256
#define WAVES  (NT / 64)
#define KSEL   16            // top-k per branch (KTOP/2)
#define CMAX   64            // candidate capacity
#define ALPHA_C 6.26f
#define PIV0   0x40133333u   // bits(2.3f): ~44 expected survivors per branch

#define BPk(raw) (((int)(raw) > 0) ? (raw) : 0u)                  // key of relu(x)
#define BNk(raw) (((int)(raw) < 0) ? ((raw) ^ 0x80000000u) : 0u)  // key of max(-x,0)
// inverted element index: smaller row index -> larger word (jax tie-break: lowest index wins)
#define INV(J,C) (~(((uint)(J) << 8) + (((uint)lane) << 2) + (uint)(C)))

// apply macro M(var, J) to all 16 named row registers — static access only, no alloca
#define ALL16(M) M(b0,0) M(b1,1) M(b2,2) M(b3,3) M(b4,4) M(b5,5) M(b6,6) M(b7,7) \
                 M(b8,8) M(b9,9) M(b10,10) M(b11,11) M(b12,12) M(b13,13) M(b14,14) M(b15,15)

__device__ __forceinline__ float wave_fadd(float v) {
#pragma unroll
  for (int off = 1; off < 64; off <<= 1) v += __shfl_xor(v, off, 64);
  return v;
}
__device__ __forceinline__ uint wave_uadd(uint v) {
#pragma unroll
  for (int off = 1; off < 64; off <<= 1) v += __shfl_xor(v, off, 64);
  return v;
}
__device__ __forceinline__ ull shflx64(ull v, int m) {
  uint lo = (uint)v, hi = (uint)(v >> 32);
  lo = __shfl_xor(lo, m, 64);
  hi = __shfl_xor(hi, m, 64);
  return (((ull)hi) << 32) | lo;
}
__device__ __forceinline__ ull shflb64(ull v, int src) {
  uint lo = (uint)v, hi = (uint)(v >> 32);
  lo = __shfl(lo, src, 64);
  hi = __shfl(hi, src, 64);
  return (((ull)hi) << 32) | lo;
}

__device__ __forceinline__ void acc_comp(uint raw, float& psum, float& nsum, uint& ic) {
  uint bp = BPk(raw), bn = BNk(raw);
  psum += __uint_as_float(bp);
  nsum += __uint_as_float(bn);
  ic += ((bp >= PIV0) ? 1u : 0u) + ((bn >= PIV0) ? 0x10000u : 0u);
}
__device__ __forceinline__ void cnt_comp(uint raw, uint mid0, uint mid1, uint& c) {
  c += ((BPk(raw) >= mid0) ? 1u : 0u) + ((BNk(raw) >= mid1) ? 0x10000u : 0u);
}
__device__ __forceinline__ void cnt2_comp(uint raw, int br, uint pivot, uint mid2, uint inv, uint& c) {
  uint k = br ? BNk(raw) : BPk(raw);
  c += ((k > pivot) || (k == pivot && inv >= mid2)) ? 1u : 0u;
}
__device__ __forceinline__ void gath_comp(uint raw, uint inv, ull S0, ull S1,
                                          ull* buf0, ull* buf1, uint* cnt0, uint* cnt1) {
  uint bp = BPk(raw);
  ull Kp = (((ull)bp) << 32) | (ull)inv;
  if (Kp >= S0) { uint s = atomicAdd(cnt0, 1u); if (s < CMAX) buf0[s] = Kp; }
  uint bn = BNk(raw);
  ull Kn = (((ull)bn) << 32) | (ull)inv;
  if (Kn >= S1) { uint s = atomicAdd(cnt1, 1u); if (s < CMAX) buf1[s] = Kn; }
}
__device__ __forceinline__ float emit_comp(uint raw, uint inv, ull T0, ull T1, float a0, float a1) {
  uint bp = BPk(raw), bn = BNk(raw);
  ull Kp = (((ull)bp) << 32) | (ull)inv;
  ull Kn = (((ull)bn) << 32) | (ull)inv;
  float r = 0.f;
  if (Kp >= T0) r  = __uint_as_float(bp) + a0;   // pv + p_tmp
  if (Kn >= T1) r -= __uint_as_float(bn) + a1;   // -(nv + n_tmp)
  return r;
}

__global__ __launch_bounds__(NT, 4) void kcomp_kernel(const float* __restrict__ x,
                                                      float* __restrict__ out) {
  const int tid  = threadIdx.x;
  const int lane = tid & 63;
  const int wid  = tid >> 6;
  const int row  = blockIdx.x * WAVES + wid;

  __shared__ ull  s_cand[WAVES][2][CMAX];
  __shared__ uint s_cnt[WAVES][2];
  if (lane == 0) { s_cnt[wid][0] = 0u; s_cnt[wid][1] = 0u; }  // same-wave DS: in-order

  const uint4* xr = reinterpret_cast<const uint4*>(x + (size_t)row * DIMS);

  // ---- load row into 16 named uint4 registers; fuse sums + initial pivot counts ----
  uint4 b0,b1,b2,b3,b4,b5,b6,b7,b8,b9,b10,b11,b12,b13,b14,b15;
  float psum = 0.f, nsum = 0.f;
  uint ic = 0;  // pos count low16, neg count high16
#define M_LOAD(V,J) { V = xr[(J)*64 + lane]; \
  acc_comp(V.x, psum, nsum, ic); acc_comp(V.y, psum, nsum, ic); \
  acc_comp(V.z, psum, nsum, ic); acc_comp(V.w, psum, nsum, ic); }
  ALL16(M_LOAD)
#undef M_LOAD

  psum = wave_fadd(psum);
  nsum = wave_fadd(nsum);
  uint cc  = wave_uadd(ic);
  uint ns0 = cc & 0xFFFFu, ns1 = cc >> 16;

  // ---- stage 1: find 32-bit key pivot with count(key >= pivot) in [KSEL, CMAX] ----
  uint lo[2], hi[2], nlo[2];
  bool done0 = (ns0 >= KSEL && ns0 <= CMAX);
  bool done1 = (ns1 >= KSEL && ns1 <= CMAX);
  bool st2_0 = false, st2_1 = false;
  lo[0]  = (ns0 >= KSEL) ? PIV0 : 0u;
  hi[0]  = (ns0 >= KSEL) ? 0xFFFFFFFFu : PIV0;
  nlo[0] = (ns0 >= KSEL) ? ns0 : (uint)DIMS;
  lo[1]  = (ns1 >= KSEL) ? PIV0 : 0u;
  hi[1]  = (ns1 >= KSEL) ? 0xFFFFFFFFu : PIV0;
  nlo[1] = (ns1 >= KSEL) ? ns1 : (uint)DIMS;

  for (int it = 0; it < 40 && !(done0 && done1); ++it) {
    uint mid0 = lo[0] + ((hi[0] - lo[0]) >> 1);
    uint mid1 = lo[1] + ((hi[1] - lo[1]) >> 1);
    uint c = 0;
#define M_CNT(V,J) { cnt_comp(V.x, mid0, mid1, c); cnt_comp(V.y, mid0, mid1, c); \
                     cnt_comp(V.z, mid0, mid1, c); cnt_comp(V.w, mid0, mid1, c); }
    ALL16(M_CNT)
#undef M_CNT
    uint t  = wave_uadd(c);
    uint t0 = t & 0xFFFFu, t1 = t >> 16;

    if (!done0) {
      if (t0 >= KSEL) { lo[0] = mid0; nlo[0] = t0; if (t0 <= CMAX) done0 = true; }
      else hi[0] = mid0;
      if (!done0 && hi[0] - lo[0] <= 1u) { done0 = true; st2_0 = (nlo[0] > CMAX); }
    }
    if (!done1) {
      if (t1 >= KSEL) { lo[1] = mid1; nlo[1] = t1; if (t1 <= CMAX) done1 = true; }
      else hi[1] = mid1;
      if (!done1 && hi[1] - lo[1] <= 1u) { done1 = true; st2_1 = (nlo[1] > CMAX); }
    }
  }

  ull S0 = ((ull)lo[0]) << 32;
  ull S1 = ((ull)lo[1]) << 32;

  // ---- stage 2 (rare): >CMAX exact 32-bit ties at pivot -> bisect the index word ----
  if (st2_0 | st2_1) {  // wave-uniform
#pragma unroll
    for (int br = 0; br < 2; ++br) {
      bool active = br ? st2_1 : st2_0;
      if (!active) continue;
      uint pivot = br ? lo[1] : lo[0];
      uint lo2 = 0u, hi2 = 0xFFFFFFFFu;
      uint nlo2 = br ? nlo[1] : nlo[0];
      for (int it = 0; it < 34 && nlo2 > CMAX; ++it) {
        uint mid2 = lo2 + ((hi2 - lo2) >> 1);
        uint c = 0;
#define M_CNT2(V,J) { cnt2_comp(V.x, br, pivot, mid2, INV(J,0), c); \
                      cnt2_comp(V.y, br, pivot, mid2, INV(J,1), c); \
                      cnt2_comp(V.z, br, pivot, mid2, INV(J,2), c); \
                      cnt2_comp(V.w, br, pivot, mid2, INV(J,3), c); }
        ALL16(M_CNT2)
#undef M_CNT2
        uint n = wave_uadd(c);
        if (n >= KSEL) { lo2 = mid2; nlo2 = n; } else hi2 = mid2;
        if (hi2 - lo2 <= 1u) break;  // unique 64-bit keys => count <= CMAX here
      }
      if (br) S1 = (((ull)pivot) << 32) | (ull)lo2;
      else    S0 = (((ull)pivot) << 32) | (ull)lo2;
    }
  }

  // ---- gather candidates (<= CMAX per branch) into this wave's LDS buffers ----
  ull*  buf0 = s_cand[wid][0];
  ull*  buf1 = s_cand[wid][1];
  uint* cnt0 = &s_cnt[wid][0];
  uint* cnt1 = &s_cnt[wid][1];
#define M_GATH(V,J) { gath_comp(V.x, INV(J,0), S0, S1, buf0, buf1, cnt0, cnt1); \
                      gath_comp(V.y, INV(J,1), S0, S1, buf0, buf1, cnt0, cnt1); \
                      gath_comp(V.z, INV(J,2), S0, S1, buf0, buf1, cnt0, cnt1); \
                      gath_comp(V.w, INV(J,3), S0, S1, buf0, buf1, cnt0, cnt1); }
  ALL16(M_GATH)
#undef M_GATH

  // ---- exact top-16 per branch: one wave bitonic-sorts both branches together ----
  uint n0 = *cnt0; if (n0 > CMAX) n0 = CMAX;   // same-wave DS: in-order, no barrier
  uint n1 = *cnt1; if (n1 > CMAX) n1 = CMAX;
  ull v0 = (lane < (int)n0) ? buf0[lane] : 0ULL;  // real keys > 0
  ull v1 = (lane < (int)n1) ? buf1[lane] : 0ULL;

#pragma unroll
  for (int k = 2; k <= 64; k <<= 1) {
#pragma unroll
    for (int j = k >> 1; j > 0; j >>= 1) {
      ull o0 = shflx64(v0, j);
      ull o1 = shflx64(v1, j);
      bool keepmin = (((lane & k) == 0) == ((lane & j) == 0));
      ull mn0 = (v0 < o0) ? v0 : o0, mx0 = (v0 < o0) ? o0 : v0;
      ull mn1 = (v1 < o1) ? v1 : o1, mx1 = (v1 < o1) ? o1 : v1;
      v0 = keepmin ? mn0 : mx0;
      v1 = keepmin ? mn1 : mx1;
    }
  }
  // ascending: top-16 in lanes 48..63; lane 48 holds the 16th-largest (threshold) key
  float tv0 = __uint_as_float((uint)(v0 >> 32));
  float tv1 = __uint_as_float((uint)(v1 >> 32));
#pragma unroll
  for (int off = 1; off < 16; off <<= 1) {
    tv0 += __shfl_xor(tv0, off, 64);
    tv1 += __shfl_xor(tv1, off, 64);
  }
  ull T0 = shflb64(v0, 48);
  ull T1 = shflb64(v1, 48);
  float a0 = ALPHA_C * (psum - __shfl(tv0, 48, 64));
  float a1 = ALPHA_C * (nsum - __shfl(tv1, 48, 64));

  // ---- emit: each lane writes back its own 64 elements (coalesced float4) ----
  float4* orow = reinterpret_cast<float4*>(out + (size_t)row * DIMS);
#define M_EMIT(V,J) { float4 o; \
  o.x = emit_comp(V.x, INV(J,0), T0, T1, a0, a1); \
  o.y = emit_comp(V.y, INV(J,1), T0, T1, a0, a1); \
  o.z = emit_comp(V.z, INV(J,2), T0, T1, a0, a1); \
  o.w = emit_comp(V.w, INV(J,3), T0, T1, a0, a1); \
  orow[(J)*64 + lane] = o; }
  ALL16(M_EMIT)
#undef M_EMIT
}

extern "C" void kernel_launch(void* const* d_in, const int* in_sizes, int n_in,
                              void* d_out, int out_size, void* d_ws, size_t ws_size,
                              hipStream_t stream) {
  const float* x = (const float*)d_in[0];
  float* o = (float*)d_out;
  const int B = in_sizes[0] / DIMS;   // 8192 rows
  const int nblocks = B / WAVES;      // 4 independent waves (rows) per block
  hipLaunchKernelGGL(kcomp_kernel, dim3(nblocks), dim3(NT), 0, stream, x, o);
}

// Round 4
// 72.754 us; speedup vs baseline: 11.2811x; 11.2811x over previous
//
#include <hip/hip_runtime.h>
#include <stdint.h>

typedef unsigned uint;
typedef unsigned long long ull;

#define DIMS   4096
#define KSEL   16            // top-k per branch (KTOP/2)
#define CMAX   64            // candidate capacity
#define ALPHA_C 6.26f
#define PIV0   0x40133333u   // bits(2.3f): ~44 expected survivors per branch
#define PIVN   0xC0133333u   // raw >= PIVN  <=>  neg-key >= PIV0

#define BPk(raw) (((int)(raw) > 0) ? (raw) : 0u)                  // key of relu(x)
#define BNk(raw) (((int)(raw) < 0) ? ((raw) ^ 0x80000000u) : 0u)  // key of max(-x,0)

__device__ __forceinline__ float wave_fadd(float v) {
#pragma unroll
  for (int off = 1; off < 64; off <<= 1) v += __shfl_xor(v, off, 64);
  return v;
}
__device__ __forceinline__ uint wave_uadd(uint v) {
#pragma unroll
  for (int off = 1; off < 64; off <<= 1) v += __shfl_xor(v, off, 64);
  return v;
}
__device__ __forceinline__ ull shflx64(ull v, int m) {
  uint lo = (uint)v, hi = (uint)(v >> 32);
  lo = __shfl_xor(lo, m, 64);
  hi = __shfl_xor(hi, m, 64);
  return (((ull)hi) << 32) | lo;
}

__global__ __launch_bounds__(64) void kcomp_kernel(const float* __restrict__ x,
                                                   float* __restrict__ out) {
  const int lane = threadIdx.x;
  const int row  = blockIdx.x;

  __shared__ uint s_row[DIMS];          // 16 KB: the row, staged via global_load_lds
  __shared__ ull  s_cand[2][CMAX];      // 1 KB: candidate keys (pos, neg)

  const float* xrow = x + (size_t)row * DIMS;
  float* orow       = out + (size_t)row * DIMS;

  // ---- zero-fill output row now; stores complete under the input loads ----
  {
    float4 z; z.x = 0.f; z.y = 0.f; z.z = 0.f; z.w = 0.f;
    float4* o4 = reinterpret_cast<float4*>(orow);
#pragma unroll
    for (int j = 0; j < 16; ++j) o4[j * 64 + lane] = z;
  }

  // ---- async global -> LDS staging (16 B/lane per chunk, no VGPR transit) ----
#pragma unroll
  for (int j = 0; j < 16; ++j) {
    __builtin_amdgcn_global_load_lds(
        (const __attribute__((address_space(1))) uint*)(xrow + j * 256 + lane * 4),
        (__attribute__((address_space(3))) uint*)&s_row[j * 256],
        16, 0, 0);
  }
  asm volatile("s_waitcnt vmcnt(0)" ::: "memory");  // drains loads AND the zero stores

  const uint4* r4 = reinterpret_cast<const uint4*>(s_row);

  // ---- pass 1: row sums + survivor counts at the statistical pivot ----
  float psum = 0.f, nmsum = 0.f;  // nmsum = sum of min(x,0)
  uint pc = 0;                    // pos count low16, neg count high16
#pragma unroll
  for (int j = 0; j < 16; ++j) {
    uint4 v = r4[j * 64 + lane];
#define ACC(RW) { float f = __uint_as_float(RW); \
    psum  += fmaxf(f, 0.f); nmsum += fminf(f, 0.f); \
    pc += (((int)(RW) >= (int)PIV0) ? 1u : 0u) + (((RW) >= PIVN) ? 0x10000u : 0u); }
    ACC(v.x) ACC(v.y) ACC(v.z) ACC(v.w)
#undef ACC
  }
  psum = wave_fadd(psum);
  float nsum = -wave_fadd(nmsum);
  uint cc  = wave_uadd(pc);
  uint ns0 = cc & 0xFFFFu, ns1 = cc >> 16;

  // ---- thresholds: typical path = PIV0; rare path = bisection over LDS ----
  ull S0, S1;
  {
    bool done0 = (ns0 >= KSEL && ns0 <= CMAX);
    bool done1 = (ns1 >= KSEL && ns1 <= CMAX);
    uint lo0 = done0 ? PIV0 : ((ns0 >= KSEL) ? PIV0 : 0u);
    uint hi0 = (ns0 >= KSEL) ? 0xFFFFFFFFu : PIV0;
    uint nlo0 = (ns0 >= KSEL) ? ns0 : (uint)DIMS;
    uint lo1 = done1 ? PIV0 : ((ns1 >= KSEL) ? PIV0 : 0u);
    uint hi1 = (ns1 >= KSEL) ? 0xFFFFFFFFu : PIV0;
    uint nlo1 = (ns1 >= KSEL) ? ns1 : (uint)DIMS;
    bool st2_0 = false, st2_1 = false;

    if (!(done0 && done1)) {  // wave-uniform: ~20/8192 rows enter
      for (int it = 0; it < 40 && !(done0 && done1); ++it) {
        uint mid0 = lo0 + ((hi0 - lo0) >> 1);
        uint mid1 = lo1 + ((hi1 - lo1) >> 1);
        uint c = 0;
        for (int j = 0; j < 16; ++j) {
          uint4 v = r4[j * 64 + lane];
#define CNT(RW) c += ((BPk(RW) >= mid0) ? 1u : 0u) + ((BNk(RW) >= mid1) ? 0x10000u : 0u);
          CNT(v.x) CNT(v.y) CNT(v.z) CNT(v.w)
#undef CNT
        }
        uint t  = wave_uadd(c);
        uint t0 = t & 0xFFFFu, t1 = t >> 16;
        if (!done0) {
          if (t0 >= KSEL) { lo0 = mid0; nlo0 = t0; if (t0 <= CMAX) done0 = true; }
          else hi0 = mid0;
          if (!done0 && hi0 - lo0 <= 1u) { done0 = true; st2_0 = (nlo0 > CMAX); }
        }
        if (!done1) {
          if (t1 >= KSEL) { lo1 = mid1; nlo1 = t1; if (t1 <= CMAX) done1 = true; }
          else hi1 = mid1;
          if (!done1 && hi1 - lo1 <= 1u) { done1 = true; st2_1 = (nlo1 > CMAX); }
        }
      }
    }
    S0 = ((ull)lo0) << 32;
    S1 = ((ull)lo1) << 32;

    // stage 2 (essentially never: >CMAX exact bit-ties): bisect the index word
    if (st2_0 | st2_1) {
      for (int br = 0; br < 2; ++br) {
        bool active = br ? st2_1 : st2_0;
        if (!active) continue;
        uint pivot = br ? lo1 : lo0;
        uint lo2 = 0u, hi2 = 0xFFFFFFFFu;
        uint nlo2 = br ? nlo1 : nlo0;
        for (int it = 0; it < 34 && nlo2 > CMAX; ++it) {
          uint mid2 = lo2 + ((hi2 - lo2) >> 1);
          uint c = 0;
          for (int j = 0; j < 16; ++j) {
            uint4 v = r4[j * 64 + lane];
#define CNT2(RW, C) { uint k = br ? BNk(RW) : BPk(RW); \
            uint inv = ~(((uint)j << 8) + ((uint)lane << 2) + (uint)(C)); \
            c += ((k > pivot) || (k == pivot && inv >= mid2)) ? 1u : 0u; }
            CNT2(v.x, 0) CNT2(v.y, 1) CNT2(v.z, 2) CNT2(v.w, 3)
#undef CNT2
          }
          uint n = wave_uadd(c);
          if (n >= KSEL) { lo2 = mid2; nlo2 = n; } else hi2 = mid2;
          if (hi2 - lo2 <= 1u) break;  // unique 64-bit keys => count <= CMAX
        }
        if (br) S1 = (((ull)pivot) << 32) | (ull)lo2;
        else    S0 = (((ull)pivot) << 32) | (ull)lo2;
      }
    }
  }

  // ---- pass 2: ballot-gather candidates into LDS (deterministic slots, no atomics) ----
  const ull ltmask = (1ull << lane) - 1ull;
  const uint lane4 = (uint)lane << 2;
  uint base0 = 0, base1 = 0;
#pragma unroll
  for (int j = 0; j < 16; ++j) {
    uint4 v = r4[j * 64 + lane];
#define GAT(RW, C) { \
    uint inv = ~(((uint)j << 8) + lane4 + (uint)(C)); \
    uint bp = BPk(RW); ull Kp = (((ull)bp) << 32) | (ull)inv; \
    bool sp = (Kp >= S0); ull mp = __ballot(sp); \
    if (sp) { uint o = base0 + (uint)__popcll(mp & ltmask); if (o < CMAX) s_cand[0][o] = Kp; } \
    base0 += (uint)__popcll(mp); \
    uint bn = BNk(RW); ull Kn = (((ull)bn) << 32) | (ull)inv; \
    bool sn = (Kn >= S1); ull mn = __ballot(sn); \
    if (sn) { uint o = base1 + (uint)__popcll(mn & ltmask); if (o < CMAX) s_cand[1][o] = Kn; } \
    base1 += (uint)__popcll(mn); }
    GAT(v.x, 0) GAT(v.y, 1) GAT(v.z, 2) GAT(v.w, 3)
#undef GAT
  }

  // ---- exact top-16 per branch: one wave bitonic-sorts both branches together ----
  uint n0 = (base0 > CMAX) ? CMAX : base0;   // same-wave DS ordering: writes visible
  uint n1 = (base1 > CMAX) ? CMAX : base1;
  ull v0 = (lane < (int)n0) ? s_cand[0][lane] : 0ull;  // real keys are nonzero
  ull v1 = (lane < (int)n1) ? s_cand[1][lane] : 0ull;

#pragma unroll
  for (int k = 2; k <= 64; k <<= 1) {
#pragma unroll
    for (int j = k >> 1; j > 0; j >>= 1) {
      ull o0 = shflx64(v0, j);
      ull o1 = shflx64(v1, j);
      bool keepmin = (((lane & k) == 0) == ((lane & j) == 0));
      ull mn0 = (v0 < o0) ? v0 : o0, mx0 = (v0 < o0) ? o0 : v0;
      ull mn1 = (v1 < o1) ? v1 : o1, mx1 = (v1 < o1) ? o1 : v1;
      v0 = keepmin ? mn0 : mx0;
      v1 = keepmin ? mn1 : mx1;
    }
  }
  // ascending: lanes 48..63 hold the top-16 of each branch

  float val0 = __uint_as_float((uint)(v0 >> 32));
  float val1 = __uint_as_float((uint)(v1 >> 32));
  float t0s = val0, t1s = val1;
#pragma unroll
  for (int off = 1; off < 16; off <<= 1) {  // 16-lane group sums; valid within [48,63]
    t0s += __shfl_xor(t0s, off, 64);
    t1s += __shfl_xor(t1s, off, 64);
  }

  // ---- scatter the 32 selected outputs (zero-fill stores already drained) ----
  if (lane >= 48) {
    float a0 = ALPHA_C * (psum - t0s);
    float a1 = ALPHA_C * (nsum - t1s);
    uint e0 = ~((uint)v0);   // low word = ~elemidx
    uint e1 = ~((uint)v1);
    orow[e0] = val0 + a0;      // pv + p_tmp
    orow[e1] = -(val1 + a1);   // -(nv + n_tmp)
  }
}

extern "C" void kernel_launch(void* const* d_in, const int* in_sizes, int n_in,
                              void* d_out, int out_size, void* d_ws, size_t ws_size,
                              hipStream_t stream) {
  const float* x = (const float*)d_in[0];
  float* o = (float*)d_out;
  const int B = in_sizes[0] / DIMS;   // 8192 rows, one wave (64-thread block) per row
  hipLaunchKernelGGL(kcomp_kernel, dim3(B), dim3(64), 0, stream, x, o);
}